// Round 2
// baseline (2057.654 us; speedup 1.0000x reference)
//
#include <hip/hip_runtime.h>
#include <math.h>

// ---------------------------------------------------------------------------
// 2-layer GCN forward — bucketed counting-split, ZERO global atomics.
// R9: transaction-latency model (rate ≈ 22 outstanding/CU ÷ miss latency).
// Restore R0's single fused pull pass (32B xs rows = ONE line-miss/edge) and
// cut that miss's latency by sorting edges with a COMPOUND key:
//   key = dst-bucket(512) * 16 + src-block(32K rows)
// so gathers walk 1MB src windows that stay resident in each XCD's 4MB L2
// (edge stream is nt so it can't evict the window). Same ordering windows
// the layer-2 h2s gathers (256KB) for free.
//   k_count    : LDS histogram over NKEY=NB*16 compound keys (nt streams)
//   k_colsum   : coalesced per-key totals ; k_scan_sums32: excl scan (1 blk)
//   k_basefill : base[blk][key] = keybase + prefix over blk (coalesced)
//   k_scatter  : 64KB LDS cursors; edge_g[pos] = pack{w:32|collow:9|row:19}
//   k_prep     : per-bucket degw -> dinv; xs = fp16(dinv*x), 32B rows
//   k_pull16_b : acc[512][13] LDS; fused epilogue relu(acc@W1+b1)@W2 -> h2s
//   k_pull2_b  : acc[512][3] LDS; out = log_softmax(dinv*(sum+self)+b2)
// Fallback: SRCB=1 (plain bucket sort) if ws tight; R1 atomic path last.
// ---------------------------------------------------------------------------

typedef unsigned long long u64;
typedef unsigned int u32;
typedef _Float16 f16;
typedef __attribute__((ext_vector_type(8))) _Float16 f16x8;

#define BKT    512        // nodes per dst bucket (collow = 9 bits)
#define NBMAX  1024       // max buckets (=> n <= 2^19, matches row:19 packing)
#define NBLK   256        // partition blocks for count/scatter
#define NKMAX  16384      // max compound keys = NBMAX * 16
#define AST1   13         // acc stride layer1 (11 feats + pad)
#define AST2   3          // acc stride layer2

// ---------------- count / scan / scatter (compound key) ----------------

__global__ __launch_bounds__(256) void k_count(const int* __restrict__ row,
                                               const int* __restrict__ col,
                                               u32* __restrict__ hist_g,
                                               int NKEY, int SRCB, int SSH,
                                               int E, int CH) {
    __shared__ u32 cnt[NKMAX];
    for (int b = threadIdx.x; b < NKEY; b += 256) cnt[b] = 0;
    __syncthreads();
    int blk = blockIdx.x;
    int s = blk * CH, e = min(s + CH, E);
    for (int i = s + threadIdx.x; i < e; i += 256) {
        int c = __builtin_nontemporal_load(col + i);
        int r = __builtin_nontemporal_load(row + i);
        int key = (c >> 9) * SRCB + (r >> SSH);
        atomicAdd(&cnt[key], 1u);              // LDS atomic
    }
    __syncthreads();
    for (int b = threadIdx.x; b < NKEY; b += 256)
        hist_g[(size_t)blk * NKEY + b] = cnt[b];   // coalesced
}

// colsum[k] = sum_j hist[j][k]   (coalesced column reduction)
__global__ __launch_bounds__(256) void k_colsum(const u32* __restrict__ hist_g,
                                                u32* __restrict__ colsum, int NKEY) {
    int k = blockIdx.x * 256 + threadIdx.x;
    if (k >= NKEY) return;
    u32 s = 0;
    for (int j = 0; j < NBLK; j++) s += hist_g[(size_t)j * NKEY + k];
    colsum[k] = s;
}

// single-block chunked EXCLUSIVE scan in place (keybase = colsum after this)
__global__ __launch_bounds__(256) void k_scan_sums32(u32* __restrict__ bsum, int nb) {
    __shared__ u32 s[256];
    __shared__ u32 carry;
    int t = threadIdx.x;
    if (t == 0) carry = 0;
    __syncthreads();
    int chunks = (nb + 255) / 256;
    for (int ch = 0; ch < chunks; ch++) {
        int i = ch * 256 + t;
        u32 v = (i < nb) ? bsum[i] : 0;
        s[t] = v;
        __syncthreads();
        for (int off = 1; off < 256; off <<= 1) {
            u32 u = (t >= off) ? s[t - off] : 0;
            __syncthreads();
            s[t] += u;
            __syncthreads();
        }
        u32 incl = s[t];
        u32 my_carry = carry;
        if (i < nb) bsum[i] = incl - v + my_carry;   // exclusive
        __syncthreads();
        if (t == 0) carry = my_carry + s[255];
        __syncthreads();
    }
}

// base[blk][k] = keybase[k] + prefix over blk of hist[.][k]  (coalesced)
__global__ __launch_bounds__(256) void k_basefill(const u32* __restrict__ hist_g,
                                                  const u32* __restrict__ keybase,
                                                  u32* __restrict__ base_g, int NKEY) {
    int k = blockIdx.x * 256 + threadIdx.x;
    if (k >= NKEY) return;
    u32 run = keybase[k];
    for (int j = 0; j < NBLK; j++) {
        base_g[(size_t)j * NKEY + k] = run;
        run += hist_g[(size_t)j * NKEY + k];
    }
}

__global__ __launch_bounds__(256) void k_scatter(const int* __restrict__ row,
                                                 const int* __restrict__ col,
                                                 const float* __restrict__ w,
                                                 const u32* __restrict__ base_g,
                                                 u64* __restrict__ edge_g,
                                                 int NKEY, int SRCB, int SSH,
                                                 int E, int CH) {
    __shared__ u32 cursor[NKMAX];
    int blk = blockIdx.x;
    for (int b = threadIdx.x; b < NKEY; b += 256)
        cursor[b] = base_g[(size_t)blk * NKEY + b];    // coalesced
    __syncthreads();
    int s = blk * CH, e = min(s + CH, E);
    for (int i = s + threadIdx.x; i < e; i += 256) {
        int c = __builtin_nontemporal_load(col + i);
        int r = __builtin_nontemporal_load(row + i);
        float wv = __builtin_nontemporal_load(w + i);
        int key = (c >> 9) * SRCB + (r >> SSH);
        u32 pos = atomicAdd(&cursor[key], 1u);         // LDS atomic
        u64 rec = ((u64)__float_as_uint(wv) << 32)
                | ((u64)(u32)(c & 511) << 19) | (u64)(u32)r;
        edge_g[pos] = rec;
    }
}

// ---------------- prep: deg -> dinv, xs = fp16(dinv * x), 32B rows ----------------

__global__ __launch_bounds__(256) void k_prep(const u64* __restrict__ edge_g,
                                              const u32* __restrict__ kb,
                                              const float* __restrict__ x,
                                              float* __restrict__ dinv_g,
                                              f16* __restrict__ xs,
                                              int SRCB, int NB, int n, int E) {
    __shared__ float degw[BKT];
    int b = blockIdx.x;
    for (int j = threadIdx.x; j < BKT; j += 256) degw[j] = 1.0f;  // self-loop
    __syncthreads();
    int s = (int)kb[(size_t)b * SRCB];
    int e = (b + 1 < NB) ? (int)kb[(size_t)(b + 1) * SRCB] : E;
    for (int i = s + threadIdx.x; i < e; i += 256) {
        u64 rec = __builtin_nontemporal_load(edge_g + i);
        int cl = (int)(((u32)rec >> 19) & 511u);
        float wv = __uint_as_float((u32)(rec >> 32));
        atomicAdd(&degw[cl], wv);                  // LDS f32 atomic
    }
    __syncthreads();
    int node0 = b << 9;
    int nn = min(BKT, n - node0);
    for (int j = threadIdx.x; j < nn; j += 256) {
        int node = node0 + j;
        float dv = rsqrtf(degw[j]);
        dinv_g[node] = dv;
        f16x8 lo, hi;
#pragma unroll
        for (int k = 0; k < 8; k++) lo[k] = (f16)(dv * x[(size_t)node * 11 + k]);
        hi[0] = (f16)(dv * x[(size_t)node * 11 + 8]);
        hi[1] = (f16)(dv * x[(size_t)node * 11 + 9]);
        hi[2] = (f16)(dv * x[(size_t)node * 11 + 10]);
        hi[3] = (f16)0.f; hi[4] = (f16)0.f; hi[5] = (f16)0.f;
        hi[6] = (f16)0.f; hi[7] = (f16)0.f;
        f16x8* dst = (f16x8*)(xs + ((size_t)node << 4));
        dst[0] = lo;
        dst[1] = hi;
    }
}

// ---------------- fused pull layer 1 (+MLP epilogue) ----------------

__global__ __launch_bounds__(512) void k_pull16_b(const u64* __restrict__ edge_g,
                                                  const u32* __restrict__ kb,
                                                  const f16* __restrict__ xs,
                                                  const float* __restrict__ dinv_g,
                                                  const float* __restrict__ W1,
                                                  const float* __restrict__ b1,
                                                  const float* __restrict__ W2,
                                                  float* __restrict__ h2s,
                                                  int SRCB, int NB, int n, int E) {
    __shared__ float acc[BKT * AST1];   // 26.6 KB
    __shared__ float sW1[176];
    __shared__ float sb1[16];
    __shared__ float sW2[32];
    for (int t = threadIdx.x; t < 176; t += 512) sW1[t] = W1[t];
    if (threadIdx.x < 16) sb1[threadIdx.x] = b1[threadIdx.x];
    if (threadIdx.x >= 64 && threadIdx.x < 96) sW2[threadIdx.x - 64] = W2[threadIdx.x - 64];
    int b = blockIdx.x;
    int node0 = b << 9;
    int nn = min(BKT, n - node0);
    // init acc with the self term xs[node]
    for (int t = threadIdx.x; t < nn * 11; t += 512) {
        int j = t / 11, k = t - j * 11;
        acc[j * AST1 + k] = (float)xs[((size_t)(node0 + j) << 4) + k];
    }
    __syncthreads();
    int s = (int)kb[(size_t)b * SRCB];
    int e = (b + 1 < NB) ? (int)kb[(size_t)(b + 1) * SRCB] : E;
    int i = s + threadIdx.x;
    // batch of 4 edges: 8 gathers issued before the dependent LDS atomics
    for (; i + 1536 < e; i += 2048) {
        u64 r0 = __builtin_nontemporal_load(edge_g + i);
        u64 r1 = __builtin_nontemporal_load(edge_g + i + 512);
        u64 r2 = __builtin_nontemporal_load(edge_g + i + 1024);
        u64 r3 = __builtin_nontemporal_load(edge_g + i + 1536);
        const f16x8* p0 = (const f16x8*)(xs + ((size_t)((u32)r0 & 0x7FFFFu) << 4));
        const f16x8* p1 = (const f16x8*)(xs + ((size_t)((u32)r1 & 0x7FFFFu) << 4));
        const f16x8* p2 = (const f16x8*)(xs + ((size_t)((u32)r2 & 0x7FFFFu) << 4));
        const f16x8* p3 = (const f16x8*)(xs + ((size_t)((u32)r3 & 0x7FFFFu) << 4));
        f16x8 a0 = p0[0], b0 = p0[1];
        f16x8 a1 = p1[0], b1v = p1[1];
        f16x8 a2 = p2[0], b2v = p2[1];
        f16x8 a3 = p3[0], b3v = p3[1];
#define PROC(rec, LO, HI) { \
        int cl = (int)(((u32)(rec) >> 19) & 511u); \
        float wv = __uint_as_float((u32)((rec) >> 32)); \
        float* a = acc + cl * AST1; \
        atomicAdd(a + 0,  wv * (float)LO[0]); atomicAdd(a + 1,  wv * (float)LO[1]); \
        atomicAdd(a + 2,  wv * (float)LO[2]); atomicAdd(a + 3,  wv * (float)LO[3]); \
        atomicAdd(a + 4,  wv * (float)LO[4]); atomicAdd(a + 5,  wv * (float)LO[5]); \
        atomicAdd(a + 6,  wv * (float)LO[6]); atomicAdd(a + 7,  wv * (float)LO[7]); \
        atomicAdd(a + 8,  wv * (float)HI[0]); atomicAdd(a + 9,  wv * (float)HI[1]); \
        atomicAdd(a + 10, wv * (float)HI[2]); }
        PROC(r0, a0, b0)
        PROC(r1, a1, b1v)
        PROC(r2, a2, b2v)
        PROC(r3, a3, b3v)
    }
    for (; i < e; i += 512) {
        u64 r0 = __builtin_nontemporal_load(edge_g + i);
        const f16x8* p0 = (const f16x8*)(xs + ((size_t)((u32)r0 & 0x7FFFFu) << 4));
        f16x8 a0 = p0[0], b0 = p0[1];
        PROC(r0, a0, b0)
    }
#undef PROC
    __syncthreads();
    // epilogue: h2s = dv * ( relu(dv*acc @ W1 + b1) @ W2 )
    for (int j = threadIdx.x; j < nn; j += 512) {
        int node = node0 + j;
        float dv = dinv_g[node];
        float v[11];
#pragma unroll
        for (int k = 0; k < 11; k++) v[k] = dv * acc[j * AST1 + k];
        float o0 = 0.f, o1 = 0.f;
#pragma unroll
        for (int f = 0; f < 16; f++) {
            float h = sb1[f];
#pragma unroll
            for (int k = 0; k < 11; k++) h += v[k] * sW1[k * 16 + f];
            h = fmaxf(h, 0.f);
            o0 += h * sW2[f * 2 + 0];
            o1 += h * sW2[f * 2 + 1];
        }
        float2 ov; ov.x = dv * o0; ov.y = dv * o1;   // h2s = dinv * h2
        *(float2*)(h2s + ((size_t)node << 1)) = ov;
    }
}

// ---------------- bucketed pull layer 2 ----------------

__global__ __launch_bounds__(512) void k_pull2_b(const u64* __restrict__ edge_g,
                                                 const u32* __restrict__ kb,
                                                 const float* __restrict__ h2s,
                                                 const float* __restrict__ dinv_g,
                                                 const float* __restrict__ b2,
                                                 float* __restrict__ out,
                                                 int SRCB, int NB, int n, int E) {
    __shared__ float acc[BKT * AST2];   // 6 KB
    int b = blockIdx.x;
    int node0 = b << 9;
    int nn = min(BKT, n - node0);
    for (int t = threadIdx.x; t < nn * 2; t += 512) {
        int j = t >> 1, f = t & 1;
        acc[j * AST2 + f] = h2s[(size_t)node0 * 2 + t];   // init with self term
    }
    __syncthreads();
    int s = (int)kb[(size_t)b * SRCB];
    int e = (b + 1 < NB) ? (int)kb[(size_t)(b + 1) * SRCB] : E;
    int i = s + threadIdx.x;
    for (; i + 3584 < e; i += 4096) {
        u64 r[8];
        float2 g[8];
#pragma unroll
        for (int q = 0; q < 8; q++)
            r[q] = __builtin_nontemporal_load(edge_g + i + q * 512);
#pragma unroll
        for (int q = 0; q < 8; q++)
            g[q] = *(const float2*)(h2s + (size_t)((u32)r[q] & 0x7FFFFu) * 2);
#pragma unroll
        for (int q = 0; q < 8; q++) {
            int cl = (int)(((u32)r[q] >> 19) & 511u);
            float wv = __uint_as_float((u32)(r[q] >> 32));
            atomicAdd(&acc[cl * AST2 + 0], wv * g[q].x);
            atomicAdd(&acc[cl * AST2 + 1], wv * g[q].y);
        }
    }
    for (; i < e; i += 512) {
        u64 rq = __builtin_nontemporal_load(edge_g + i);
        float2 gq = *(const float2*)(h2s + (size_t)((u32)rq & 0x7FFFFu) * 2);
        int cl = (int)(((u32)rq >> 19) & 511u);
        float wv = __uint_as_float((u32)(rq >> 32));
        atomicAdd(&acc[cl * AST2 + 0], wv * gq.x);
        atomicAdd(&acc[cl * AST2 + 1], wv * gq.y);
    }
    __syncthreads();
    float c0 = b2[0], c1 = b2[1];
    for (int j = threadIdx.x; j < nn; j += 512) {
        int node = node0 + j;
        float dv = dinv_g[node];
        float v0 = dv * acc[j * AST2 + 0] + c0;
        float v1 = dv * acc[j * AST2 + 1] + c1;
        float m = fmaxf(v0, v1);
        float lse = m + logf(expf(v0 - m) + expf(v1 - m));
        float2 ov; ov.x = v0 - lse; ov.y = v1 - lse;
        *(float2*)(out + (size_t)node * 2) = ov;
    }
}

// ---------------- fallback atomic-scatter kernels (R1 proven path) ----------------

__global__ __launch_bounds__(256) void k_init_deg(float* deg, int n) {
    int i = blockIdx.x * blockDim.x + threadIdx.x;
    if (i < n) deg[i] = 1.0f;
}

__global__ __launch_bounds__(256) void k_deg_accum(const int* __restrict__ col,
                                                   const float* __restrict__ w,
                                                   float* __restrict__ deg, int E) {
    int i = blockIdx.x * blockDim.x + threadIdx.x;
    if (i < E) atomicAdd(&deg[col[i]], w[i]);
}

__global__ __launch_bounds__(256) void k_rsqrt(float* deg, int n) {
    int i = blockIdx.x * blockDim.x + threadIdx.x;
    if (i < n) {
        float d = deg[i];
        deg[i] = (d > 0.0f) ? rsqrtf(d) : 0.0f;
    }
}

__global__ __launch_bounds__(256) void k_gemm1_plain(const float* __restrict__ x,
                                                     const float* __restrict__ W1,
                                                     float* __restrict__ h1, int n) {
    __shared__ float sW[176];
    for (int t = threadIdx.x; t < 176; t += blockDim.x) sW[t] = W1[t];
    __syncthreads();
    int i = blockIdx.x * blockDim.x + threadIdx.x;
    if (i >= n) return;
    float xi[11];
#pragma unroll
    for (int k = 0; k < 11; k++) xi[k] = x[(size_t)i * 11 + k];
#pragma unroll
    for (int f = 0; f < 16; f++) {
        float acc = 0.0f;
#pragma unroll
        for (int k = 0; k < 11; k++) acc += xi[k] * sW[k * 16 + f];
        h1[(size_t)i * 16 + f] = acc;
    }
}

__global__ __launch_bounds__(256) void k_scatter16(const int* __restrict__ row,
                                                   const int* __restrict__ col,
                                                   const float* __restrict__ w,
                                                   const float* __restrict__ dinv,
                                                   const float* __restrict__ h1,
                                                   float* __restrict__ acc, int E) {
    int i = blockIdx.x * blockDim.x + threadIdx.x;
    if (i >= E) return;
    int r = row[i], c = col[i];
    float nw = dinv[r] * w[i] * dinv[c];
    const float4* hr = (const float4*)(h1 + (size_t)r * 16);
    float* o = acc + (size_t)c * 16;
#pragma unroll
    for (int q = 0; q < 4; q++) {
        float4 hv = hr[q];
        atomicAdd(o + q * 4 + 0, nw * hv.x);
        atomicAdd(o + q * 4 + 1, nw * hv.y);
        atomicAdd(o + q * 4 + 2, nw * hv.z);
        atomicAdd(o + q * 4 + 3, nw * hv.w);
    }
}

__global__ __launch_bounds__(256) void k_post1(const float* __restrict__ h1,
                                               const float* __restrict__ dinv,
                                               const float* __restrict__ b1,
                                               float* __restrict__ acc, int n) {
    int i = blockIdx.x * blockDim.x + threadIdx.x;
    if (i >= n) return;
    float dv = dinv[i];
    float cs = dv * dv;
#pragma unroll
    for (int f = 0; f < 16; f++) {
        float v = acc[(size_t)i * 16 + f] + cs * h1[(size_t)i * 16 + f] + b1[f];
        acc[(size_t)i * 16 + f] = v > 0.0f ? v : 0.0f;
    }
}

__global__ __launch_bounds__(256) void k_gemm2(const float* __restrict__ hrelu,
                                               const float* __restrict__ W2,
                                               float* __restrict__ h2, int n) {
    __shared__ float sW[32];
    for (int t = threadIdx.x; t < 32; t += blockDim.x) sW[t] = W2[t];
    __syncthreads();
    int i = blockIdx.x * blockDim.x + threadIdx.x;
    if (i >= n) return;
    float a0 = 0.0f, a1 = 0.0f;
#pragma unroll
    for (int f = 0; f < 16; f++) {
        float h = hrelu[(size_t)i * 16 + f];
        a0 += h * sW[f * 2 + 0];
        a1 += h * sW[f * 2 + 1];
    }
    h2[(size_t)i * 2 + 0] = a0;
    h2[(size_t)i * 2 + 1] = a1;
}

__global__ __launch_bounds__(256) void k_scatter2(const int* __restrict__ row,
                                                  const int* __restrict__ col,
                                                  const float* __restrict__ w,
                                                  const float* __restrict__ dinv,
                                                  const float* __restrict__ h2,
                                                  float* __restrict__ out, int E) {
    int i = blockIdx.x * blockDim.x + threadIdx.x;
    if (i >= E) return;
    int r = row[i], c = col[i];
    float nw = dinv[r] * w[i] * dinv[c];
    atomicAdd(&out[(size_t)c * 2 + 0], nw * h2[(size_t)r * 2 + 0]);
    atomicAdd(&out[(size_t)c * 2 + 1], nw * h2[(size_t)r * 2 + 1]);
}

__global__ __launch_bounds__(256) void k_final(const float* __restrict__ h2,
                                               const float* __restrict__ dinv,
                                               const float* __restrict__ b2,
                                               float* __restrict__ out, int n) {
    int i = blockIdx.x * blockDim.x + threadIdx.x;
    if (i >= n) return;
    float dv = dinv[i];
    float cs = dv * dv;
    float v0 = out[(size_t)i * 2 + 0] + cs * h2[(size_t)i * 2 + 0] + b2[0];
    float v1 = out[(size_t)i * 2 + 1] + cs * h2[(size_t)i * 2 + 1] + b2[1];
    float m = fmaxf(v0, v1);
    float lse = m + logf(expf(v0 - m) + expf(v1 - m));
    out[(size_t)i * 2 + 0] = v0 - lse;
    out[(size_t)i * 2 + 1] = v1 - lse;
}

// ---------------- launch ----------------

static inline size_t align64(size_t x) { return (x + 63) & ~(size_t)63; }

extern "C" void kernel_launch(void* const* d_in, const int* in_sizes, int n_in,
                              void* d_out, int out_size, void* d_ws, size_t ws_size,
                              hipStream_t stream) {
    const float* x  = (const float*)d_in[0];
    const int*   ei = (const int*)d_in[1];
    const float* ew = (const float*)d_in[2];
    const float* W1 = (const float*)d_in[3];
    const float* b1 = (const float*)d_in[4];
    const float* W2 = (const float*)d_in[5];
    const float* b2 = (const float*)d_in[6];

    const int n = in_sizes[0] / 11;
    const int E = in_sizes[2];
    const int* rowp = ei;       // sources
    const int* colp = ei + E;   // targets

    const int TB = 256;
    const int gN = (n + TB - 1) / TB;
    const int gE = (E + TB - 1) / TB;

    const int NB = (n + BKT - 1) / BKT;            // dst buckets
    const int CH = (E + NBLK - 1) / NBLK;          // edges per partition block

    float* outf = (float*)d_out;

    // pick SRCB (src-window count): 16 -> 32K-row windows (1MB xs working set)
    int SRCB = 16, SSH = 15;
    size_t needed = 0;
    size_t o_hist, o_base, o_kb, o_dinv, o_xs, o_h2, o_edge;
    for (int attempt = 0; attempt < 2; attempt++) {
        int NKEY = NB * SRCB;
        size_t M = (size_t)NKEY * NBLK;
        o_hist = 0;
        o_base = align64(o_hist + M * 4);
        o_kb   = align64(o_base + M * 4);
        o_dinv = align64(o_kb + (size_t)NKEY * 4);
        o_xs   = align64(o_dinv + (size_t)n * 4);
        o_h2   = align64(o_xs + (size_t)n * 16 * 2);
        o_edge = align64(o_h2 + (size_t)n * 2 * 4);
        needed = align64(o_edge + (size_t)E * 8);
        if (ws_size >= needed) break;
        SRCB = 1; SSH = 19;                        // plain bucket sort fallback
    }

    if (ws_size >= needed && n <= (1 << 19) && NB <= NBMAX && NB * SRCB <= NKMAX) {
        char* base = (char*)d_ws;
        u32*   hist_g = (u32*)(base + o_hist);
        u32*   base_g = (u32*)(base + o_base);
        u32*   kb     = (u32*)(base + o_kb);
        float* dinv_g = (float*)(base + o_dinv);
        f16*   xs     = (f16*)(base + o_xs);
        float* h2s    = (float*)(base + o_h2);
        u64*   edge_g = (u64*)(base + o_edge);

        const int NKEY = NB * SRCB;
        const int KB = (NKEY + 255) / 256;

        k_count<<<NBLK, TB, 0, stream>>>(rowp, colp, hist_g, NKEY, SRCB, SSH, E, CH);
        k_colsum<<<KB, TB, 0, stream>>>(hist_g, kb, NKEY);
        k_scan_sums32<<<1, TB, 0, stream>>>(kb, NKEY);          // kb -> exclusive keybase
        k_basefill<<<KB, TB, 0, stream>>>(hist_g, kb, base_g, NKEY);
        k_scatter<<<NBLK, TB, 0, stream>>>(rowp, colp, ew, base_g, edge_g,
                                           NKEY, SRCB, SSH, E, CH);
        k_prep<<<NB, TB, 0, stream>>>(edge_g, kb, x, dinv_g, xs, SRCB, NB, n, E);
        k_pull16_b<<<NB, 512, 0, stream>>>(edge_g, kb, xs, dinv_g, W1, b1, W2, h2s,
                                           SRCB, NB, n, E);
        k_pull2_b<<<NB, 512, 0, stream>>>(edge_g, kb, h2s, dinv_g, b2, outf,
                                          SRCB, NB, n, E);
    } else {
        // fallback: atomic-scatter path (R1)
        float* ws   = (float*)d_ws;
        float* dinv = ws;
        float* h1   = ws + (size_t)n;
        float* acc1 = ws + (size_t)n * 17;

        k_init_deg<<<gN, TB, 0, stream>>>(dinv, n);
        k_deg_accum<<<gE, TB, 0, stream>>>(colp, ew, dinv, E);
        k_rsqrt<<<gN, TB, 0, stream>>>(dinv, n);

        k_gemm1_plain<<<gN, TB, 0, stream>>>(x, W1, h1, n);
        hipMemsetAsync(acc1, 0, (size_t)n * 16 * sizeof(float), stream);
        k_scatter16<<<gE, TB, 0, stream>>>(rowp, colp, ew, dinv, h1, acc1, E);
        k_post1<<<gN, TB, 0, stream>>>(h1, dinv, b1, acc1, n);

        float* h2 = h1;
        k_gemm2<<<gN, TB, 0, stream>>>(acc1, W2, h2, n);
        hipMemsetAsync(outf, 0, (size_t)n * 2 * sizeof(float), stream);
        k_scatter2<<<gE, TB, 0, stream>>>(rowp, colp, ew, dinv, h2, outf, E);
        k_final<<<gN, TB, 0, stream>>>(h2, dinv, b2, outf, n);
    }
}

// Round 3
// 1593.594 us; speedup vs baseline: 1.2912x; 1.2912x over previous
//
#include <hip/hip_runtime.h>
#include <math.h>

// ---------------------------------------------------------------------------
// 2-layer GCN forward — bucketed counting-split, ZERO global atomics.
// R10: measured model (R8/R9 2-point fit): LDS atomic ≈ 3.2 cy each; the old
// pull16 spent 35/36 cy/edge on its 11 ds_add_f32. Eliminate them:
// in-block CSR. Each 512-dst bucket block:
//   P1 LDS histogram cnt[512] (1 atomic/edge)
//   P2 512-wide LDS scan
//   P3 scatter recs dst-sorted into edge2_g via LDS cursors (1 atomic/edge);
//      persist run starts -> runstart[n]
//   P4 thread j owns dst j: register accumulation of 11 feats (0 atomics),
//      fused MLP epilogue (relu(acc@W1+b1)@W2) -> h2s
// k_pull2_csr then reuses the dst-sorted edge2 + runstart: pure per-node CSR
// loop, no LDS, no atomics.
// Global pre-sort keyed (dst-bucket x 8 src-windows) keeps P4 gathers inside
// a 2MB L2-resident xs window. Fallback: R9 atomic pull kernels if ws tight;
// R1 atomic-scatter path last.
// ---------------------------------------------------------------------------

typedef unsigned long long u64;
typedef unsigned int u32;
typedef _Float16 f16;
typedef __attribute__((ext_vector_type(8))) _Float16 f16x8;

#define BKT    512        // nodes per dst bucket (collow = 9 bits)
#define NBMAX  1024       // max buckets (=> n <= 2^19, matches row:19 packing)
#define NBLK   256        // partition blocks for count/scatter
#define NKMAX  8192       // max compound keys = NBMAX * 8
#define AST1   13         // acc stride layer1 (atomic fallback)
#define AST2   3          // acc stride layer2 (atomic fallback)

// ---------------- count / scan / scatter (compound key) ----------------

__global__ __launch_bounds__(256) void k_count(const int* __restrict__ row,
                                               const int* __restrict__ col,
                                               u32* __restrict__ hist_g,
                                               int NKEY, int SRCB, int SSH,
                                               int E, int CH) {
    __shared__ u32 cnt[NKMAX];
    for (int b = threadIdx.x; b < NKEY; b += 256) cnt[b] = 0;
    __syncthreads();
    int blk = blockIdx.x;
    int s = blk * CH, e = min(s + CH, E);
    for (int i = s + threadIdx.x; i < e; i += 256) {
        int c = __builtin_nontemporal_load(col + i);
        int r = __builtin_nontemporal_load(row + i);
        int key = (c >> 9) * SRCB + (r >> SSH);
        atomicAdd(&cnt[key], 1u);              // LDS atomic
    }
    __syncthreads();
    for (int b = threadIdx.x; b < NKEY; b += 256)
        hist_g[(size_t)blk * NKEY + b] = cnt[b];   // coalesced
}

// colsum[k] = sum_j hist[j][k]   (coalesced column reduction)
__global__ __launch_bounds__(256) void k_colsum(const u32* __restrict__ hist_g,
                                                u32* __restrict__ colsum, int NKEY) {
    int k = blockIdx.x * 256 + threadIdx.x;
    if (k >= NKEY) return;
    u32 s = 0;
    for (int j = 0; j < NBLK; j++) s += hist_g[(size_t)j * NKEY + k];
    colsum[k] = s;
}

// single-block chunked EXCLUSIVE scan in place (keybase = colsum after this)
__global__ __launch_bounds__(256) void k_scan_sums32(u32* __restrict__ bsum, int nb) {
    __shared__ u32 s[256];
    __shared__ u32 carry;
    int t = threadIdx.x;
    if (t == 0) carry = 0;
    __syncthreads();
    int chunks = (nb + 255) / 256;
    for (int ch = 0; ch < chunks; ch++) {
        int i = ch * 256 + t;
        u32 v = (i < nb) ? bsum[i] : 0;
        s[t] = v;
        __syncthreads();
        for (int off = 1; off < 256; off <<= 1) {
            u32 u = (t >= off) ? s[t - off] : 0;
            __syncthreads();
            s[t] += u;
            __syncthreads();
        }
        u32 incl = s[t];
        u32 my_carry = carry;
        if (i < nb) bsum[i] = incl - v + my_carry;   // exclusive
        __syncthreads();
        if (t == 0) carry = my_carry + s[255];
        __syncthreads();
    }
}

// base[blk][k] = keybase[k] + prefix over blk of hist[.][k]  (coalesced)
__global__ __launch_bounds__(256) void k_basefill(const u32* __restrict__ hist_g,
                                                  const u32* __restrict__ keybase,
                                                  u32* __restrict__ base_g, int NKEY) {
    int k = blockIdx.x * 256 + threadIdx.x;
    if (k >= NKEY) return;
    u32 run = keybase[k];
    for (int j = 0; j < NBLK; j++) {
        base_g[(size_t)j * NKEY + k] = run;
        run += hist_g[(size_t)j * NKEY + k];
    }
}

__global__ __launch_bounds__(256) void k_scatter(const int* __restrict__ row,
                                                 const int* __restrict__ col,
                                                 const float* __restrict__ w,
                                                 const u32* __restrict__ base_g,
                                                 u64* __restrict__ edge_g,
                                                 int NKEY, int SRCB, int SSH,
                                                 int E, int CH) {
    __shared__ u32 cursor[NKMAX];
    int blk = blockIdx.x;
    for (int b = threadIdx.x; b < NKEY; b += 256)
        cursor[b] = base_g[(size_t)blk * NKEY + b];    // coalesced
    __syncthreads();
    int s = blk * CH, e = min(s + CH, E);
    for (int i = s + threadIdx.x; i < e; i += 256) {
        int c = __builtin_nontemporal_load(col + i);
        int r = __builtin_nontemporal_load(row + i);
        float wv = __builtin_nontemporal_load(w + i);
        int key = (c >> 9) * SRCB + (r >> SSH);
        u32 pos = atomicAdd(&cursor[key], 1u);         // LDS atomic
        u64 rec = ((u64)__float_as_uint(wv) << 32)
                | ((u64)(u32)(c & 511) << 19) | (u64)(u32)r;
        edge_g[pos] = rec;
    }
}

// ---------------- prep: deg -> dinv, xs = fp16(dinv * x), 32B rows ----------------

__global__ __launch_bounds__(256) void k_prep(const u64* __restrict__ edge_g,
                                              const u32* __restrict__ kb,
                                              const float* __restrict__ x,
                                              float* __restrict__ dinv_g,
                                              f16* __restrict__ xs,
                                              int SRCB, int NB, int n, int E) {
    __shared__ float degw[BKT];
    int b = blockIdx.x;
    for (int j = threadIdx.x; j < BKT; j += 256) degw[j] = 1.0f;  // self-loop
    __syncthreads();
    int s = (int)kb[(size_t)b * SRCB];
    int e = (b + 1 < NB) ? (int)kb[(size_t)(b + 1) * SRCB] : E;
    for (int i = s + threadIdx.x; i < e; i += 256) {
        u64 rec = __builtin_nontemporal_load(edge_g + i);
        int cl = (int)(((u32)rec >> 19) & 511u);
        float wv = __uint_as_float((u32)(rec >> 32));
        atomicAdd(&degw[cl], wv);                  // LDS f32 atomic
    }
    __syncthreads();
    int node0 = b << 9;
    int nn = min(BKT, n - node0);
    for (int j = threadIdx.x; j < nn; j += 256) {
        int node = node0 + j;
        float dv = rsqrtf(degw[j]);
        dinv_g[node] = dv;
        f16x8 lo, hi;
#pragma unroll
        for (int k = 0; k < 8; k++) lo[k] = (f16)(dv * x[(size_t)node * 11 + k]);
        hi[0] = (f16)(dv * x[(size_t)node * 11 + 8]);
        hi[1] = (f16)(dv * x[(size_t)node * 11 + 9]);
        hi[2] = (f16)(dv * x[(size_t)node * 11 + 10]);
        hi[3] = (f16)0.f; hi[4] = (f16)0.f; hi[5] = (f16)0.f;
        hi[6] = (f16)0.f; hi[7] = (f16)0.f;
        f16x8* dst = (f16x8*)(xs + ((size_t)node << 4));
        dst[0] = lo;
        dst[1] = hi;
    }
}

// ---------------- CSR pull layer 1 (in-block dst sort + register accum) ----------------

__global__ __launch_bounds__(512) void k_pull16_csr(const u64* __restrict__ edge_g,
                                                    const u32* __restrict__ kb,
                                                    u64* __restrict__ edge2_g,
                                                    u32* __restrict__ runstart,
                                                    const f16* __restrict__ xs,
                                                    const float* __restrict__ dinv_g,
                                                    const float* __restrict__ W1,
                                                    const float* __restrict__ b1,
                                                    const float* __restrict__ W2,
                                                    float* __restrict__ h2s,
                                                    int SRCB, int NB, int n, int E) {
    __shared__ u32 cnt[BKT];
    __shared__ u32 off[BKT];
    __shared__ u32 cur[BKT];
    __shared__ float sW1[176];
    __shared__ float sb1[16];
    __shared__ float sW2[32];
    int t = threadIdx.x;
    for (int q = t; q < 176; q += 512) sW1[q] = W1[q];
    if (t < 16) sb1[t] = b1[t];
    if (t >= 32 && t < 64) sW2[t - 32] = W2[t - 32];
    int b = blockIdx.x;
    int node0 = b << 9;
    int s = (int)kb[(size_t)b * SRCB];
    int e = (b + 1 < NB) ? (int)kb[(size_t)(b + 1) * SRCB] : E;
    cnt[t] = 0;
    __syncthreads();
    // P1: per-dst histogram (1 LDS atomic / edge)
    for (int i = s + t; i < e; i += 512) {
        u32 lo = (u32)edge_g[i];
        atomicAdd(&cnt[(lo >> 19) & 511u], 1u);
    }
    __syncthreads();
    // P2: inclusive Hillis-Steele scan over 512
    off[t] = cnt[t];
    __syncthreads();
    for (int d = 1; d < 512; d <<= 1) {
        u32 v = (t >= d) ? off[t - d] : 0;
        __syncthreads();
        off[t] += v;
        __syncthreads();
    }
    u32 mystart = (u32)s + off[t] - cnt[t];     // exclusive start of run t
    cur[t] = mystart;
    runstart[node0 + t] = mystart;              // persisted for k_pull2_csr
    __syncthreads();
    // P3: scatter recs dst-sorted into edge2 (1 LDS atomic / edge)
    for (int i = s + t; i < e; i += 512) {
        u64 rec = edge_g[i];
        int cl = (int)(((u32)rec >> 19) & 511u);
        u32 pos = atomicAdd(&cur[cl], 1u);
        edge2_g[pos] = rec;
    }
    __syncthreads();   // vmcnt(0) drain before barrier -> edge2 visible in-block
    // P4: thread t owns dst node0+t, register accumulation (0 atomics)
    int nn = min(BKT, n - node0);
    if (t < nn) {
        int node = node0 + t;
        float a[11];
        const f16x8* self = (const f16x8*)(xs + ((size_t)node << 4));
        f16x8 slo = self[0], shi = self[1];
#pragma unroll
        for (int k = 0; k < 8; k++) a[k] = (float)slo[k];
        a[8] = (float)shi[0]; a[9] = (float)shi[1]; a[10] = (float)shi[2];
        int p = (int)mystart, pe = p + (int)cnt[t];
        for (; p + 1 < pe; p += 2) {
            u64 r0 = __builtin_nontemporal_load(edge2_g + p);
            u64 r1 = __builtin_nontemporal_load(edge2_g + p + 1);
            const f16x8* q0 = (const f16x8*)(xs + ((size_t)((u32)r0 & 0x7FFFFu) << 4));
            const f16x8* q1 = (const f16x8*)(xs + ((size_t)((u32)r1 & 0x7FFFFu) << 4));
            f16x8 l0 = q0[0], h0 = q0[1];
            f16x8 l1 = q1[0], h1 = q1[1];
            float w0 = __uint_as_float((u32)(r0 >> 32));
            float w1 = __uint_as_float((u32)(r1 >> 32));
#pragma unroll
            for (int k = 0; k < 8; k++) a[k] += w0 * (float)l0[k];
            a[8] += w0 * (float)h0[0]; a[9] += w0 * (float)h0[1]; a[10] += w0 * (float)h0[2];
#pragma unroll
            for (int k = 0; k < 8; k++) a[k] += w1 * (float)l1[k];
            a[8] += w1 * (float)h1[0]; a[9] += w1 * (float)h1[1]; a[10] += w1 * (float)h1[2];
        }
        if (p < pe) {
            u64 r0 = edge2_g[p];
            const f16x8* q0 = (const f16x8*)(xs + ((size_t)((u32)r0 & 0x7FFFFu) << 4));
            f16x8 l0 = q0[0], h0 = q0[1];
            float w0 = __uint_as_float((u32)(r0 >> 32));
#pragma unroll
            for (int k = 0; k < 8; k++) a[k] += w0 * (float)l0[k];
            a[8] += w0 * (float)h0[0]; a[9] += w0 * (float)h0[1]; a[10] += w0 * (float)h0[2];
        }
        // epilogue: h2s = dv * ( relu(dv*a @ W1 + b1) @ W2 )
        float dv = dinv_g[node];
#pragma unroll
        for (int k = 0; k < 11; k++) a[k] *= dv;
        float o0 = 0.f, o1 = 0.f;
#pragma unroll
        for (int f = 0; f < 16; f++) {
            float h = sb1[f];
#pragma unroll
            for (int k = 0; k < 11; k++) h += a[k] * sW1[k * 16 + f];
            h = fmaxf(h, 0.f);
            o0 += h * sW2[f * 2 + 0];
            o1 += h * sW2[f * 2 + 1];
        }
        float2 ov; ov.x = dv * o0; ov.y = dv * o1;   // h2s = dinv * h2
        *(float2*)(h2s + ((size_t)node << 1)) = ov;
    }
}

// ---------------- CSR pull layer 2 (no LDS, no atomics) ----------------

__global__ __launch_bounds__(256) void k_pull2_csr(const u64* __restrict__ edge2_g,
                                                   const u32* __restrict__ runstart,
                                                   const float* __restrict__ h2s,
                                                   const float* __restrict__ dinv_g,
                                                   const float* __restrict__ b2,
                                                   float* __restrict__ out, int n) {
    int node = blockIdx.x * 256 + threadIdx.x;
    if (node >= n) return;
    float2 selfv = *(const float2*)(h2s + (size_t)node * 2);
    float a0 = selfv.x, a1 = selfv.y;
    int p = (int)runstart[node], pe = (int)runstart[node + 1];
    for (; p + 1 < pe; p += 2) {
        u64 r0 = __builtin_nontemporal_load(edge2_g + p);
        u64 r1 = __builtin_nontemporal_load(edge2_g + p + 1);
        float2 g0 = *(const float2*)(h2s + (size_t)((u32)r0 & 0x7FFFFu) * 2);
        float2 g1 = *(const float2*)(h2s + (size_t)((u32)r1 & 0x7FFFFu) * 2);
        float w0 = __uint_as_float((u32)(r0 >> 32));
        float w1 = __uint_as_float((u32)(r1 >> 32));
        a0 += w0 * g0.x + w1 * g1.x;
        a1 += w0 * g0.y + w1 * g1.y;
    }
    if (p < pe) {
        u64 r0 = edge2_g[p];
        float2 g0 = *(const float2*)(h2s + (size_t)((u32)r0 & 0x7FFFFu) * 2);
        float w0 = __uint_as_float((u32)(r0 >> 32));
        a0 += w0 * g0.x;
        a1 += w0 * g0.y;
    }
    float dv = dinv_g[node];
    float v0 = dv * a0 + b2[0];
    float v1 = dv * a1 + b2[1];
    float m = fmaxf(v0, v1);
    float lse = m + logf(expf(v0 - m) + expf(v1 - m));
    float2 ov; ov.x = v0 - lse; ov.y = v1 - lse;
    *(float2*)(out + (size_t)node * 2) = ov;
}

// ---------------- atomic pull fallbacks (R9 proven, used if ws tight) ----------------

__global__ __launch_bounds__(512) void k_pull16_atomic(const u64* __restrict__ edge_g,
                                                       const u32* __restrict__ kb,
                                                       const f16* __restrict__ xs,
                                                       const float* __restrict__ dinv_g,
                                                       const float* __restrict__ W1,
                                                       const float* __restrict__ b1,
                                                       const float* __restrict__ W2,
                                                       float* __restrict__ h2s,
                                                       int SRCB, int NB, int n, int E) {
    __shared__ float acc[BKT * AST1];
    __shared__ float sW1[176];
    __shared__ float sb1[16];
    __shared__ float sW2[32];
    for (int t = threadIdx.x; t < 176; t += 512) sW1[t] = W1[t];
    if (threadIdx.x < 16) sb1[threadIdx.x] = b1[threadIdx.x];
    if (threadIdx.x >= 64 && threadIdx.x < 96) sW2[threadIdx.x - 64] = W2[threadIdx.x - 64];
    int b = blockIdx.x;
    int node0 = b << 9;
    int nn = min(BKT, n - node0);
    for (int t = threadIdx.x; t < nn * 11; t += 512) {
        int j = t / 11, k = t - j * 11;
        acc[j * AST1 + k] = (float)xs[((size_t)(node0 + j) << 4) + k];
    }
    __syncthreads();
    int s = (int)kb[(size_t)b * SRCB];
    int e = (b + 1 < NB) ? (int)kb[(size_t)(b + 1) * SRCB] : E;
    int i = s + threadIdx.x;
    for (; i < e; i += 512) {
        u64 r0 = __builtin_nontemporal_load(edge_g + i);
        const f16x8* p0 = (const f16x8*)(xs + ((size_t)((u32)r0 & 0x7FFFFu) << 4));
        f16x8 a0 = p0[0], b0 = p0[1];
        int cl = (int)(((u32)r0 >> 19) & 511u);
        float wv = __uint_as_float((u32)(r0 >> 32));
        float* a = acc + cl * AST1;
        atomicAdd(a + 0,  wv * (float)a0[0]); atomicAdd(a + 1,  wv * (float)a0[1]);
        atomicAdd(a + 2,  wv * (float)a0[2]); atomicAdd(a + 3,  wv * (float)a0[3]);
        atomicAdd(a + 4,  wv * (float)a0[4]); atomicAdd(a + 5,  wv * (float)a0[5]);
        atomicAdd(a + 6,  wv * (float)a0[6]); atomicAdd(a + 7,  wv * (float)a0[7]);
        atomicAdd(a + 8,  wv * (float)b0[0]); atomicAdd(a + 9,  wv * (float)b0[1]);
        atomicAdd(a + 10, wv * (float)b0[2]);
    }
    __syncthreads();
    for (int j = threadIdx.x; j < nn; j += 512) {
        int node = node0 + j;
        float dv = dinv_g[node];
        float v[11];
#pragma unroll
        for (int k = 0; k < 11; k++) v[k] = dv * acc[j * AST1 + k];
        float o0 = 0.f, o1 = 0.f;
#pragma unroll
        for (int f = 0; f < 16; f++) {
            float h = sb1[f];
#pragma unroll
            for (int k = 0; k < 11; k++) h += v[k] * sW1[k * 16 + f];
            h = fmaxf(h, 0.f);
            o0 += h * sW2[f * 2 + 0];
            o1 += h * sW2[f * 2 + 1];
        }
        float2 ov; ov.x = dv * o0; ov.y = dv * o1;
        *(float2*)(h2s + ((size_t)node << 1)) = ov;
    }
}

__global__ __launch_bounds__(512) void k_pull2_atomic(const u64* __restrict__ edge_g,
                                                      const u32* __restrict__ kb,
                                                      const float* __restrict__ h2s,
                                                      const float* __restrict__ dinv_g,
                                                      const float* __restrict__ b2,
                                                      float* __restrict__ out,
                                                      int SRCB, int NB, int n, int E) {
    __shared__ float acc[BKT * AST2];
    int b = blockIdx.x;
    int node0 = b << 9;
    int nn = min(BKT, n - node0);
    for (int t = threadIdx.x; t < nn * 2; t += 512) {
        int j = t >> 1, f = t & 1;
        acc[j * AST2 + f] = h2s[(size_t)node0 * 2 + t];
    }
    __syncthreads();
    int s = (int)kb[(size_t)b * SRCB];
    int e = (b + 1 < NB) ? (int)kb[(size_t)(b + 1) * SRCB] : E;
    for (int i = s + threadIdx.x; i < e; i += 512) {
        u64 rq = __builtin_nontemporal_load(edge_g + i);
        float2 gq = *(const float2*)(h2s + (size_t)((u32)rq & 0x7FFFFu) * 2);
        int cl = (int)(((u32)rq >> 19) & 511u);
        float wv = __uint_as_float((u32)(rq >> 32));
        atomicAdd(&acc[cl * AST2 + 0], wv * gq.x);
        atomicAdd(&acc[cl * AST2 + 1], wv * gq.y);
    }
    __syncthreads();
    float c0 = b2[0], c1 = b2[1];
    for (int j = threadIdx.x; j < nn; j += 512) {
        int node = node0 + j;
        float dv = dinv_g[node];
        float v0 = dv * acc[j * AST2 + 0] + c0;
        float v1 = dv * acc[j * AST2 + 1] + c1;
        float m = fmaxf(v0, v1);
        float lse = m + logf(expf(v0 - m) + expf(v1 - m));
        float2 ov; ov.x = v0 - lse; ov.y = v1 - lse;
        *(float2*)(out + (size_t)node * 2) = ov;
    }
}

// ---------------- fallback atomic-scatter kernels (R1 proven path) ----------------

__global__ __launch_bounds__(256) void k_init_deg(float* deg, int n) {
    int i = blockIdx.x * blockDim.x + threadIdx.x;
    if (i < n) deg[i] = 1.0f;
}

__global__ __launch_bounds__(256) void k_deg_accum(const int* __restrict__ col,
                                                   const float* __restrict__ w,
                                                   float* __restrict__ deg, int E) {
    int i = blockIdx.x * blockDim.x + threadIdx.x;
    if (i < E) atomicAdd(&deg[col[i]], w[i]);
}

__global__ __launch_bounds__(256) void k_rsqrt(float* deg, int n) {
    int i = blockIdx.x * blockDim.x + threadIdx.x;
    if (i < n) {
        float d = deg[i];
        deg[i] = (d > 0.0f) ? rsqrtf(d) : 0.0f;
    }
}

__global__ __launch_bounds__(256) void k_gemm1_plain(const float* __restrict__ x,
                                                     const float* __restrict__ W1,
                                                     float* __restrict__ h1, int n) {
    __shared__ float sW[176];
    for (int t = threadIdx.x; t < 176; t += blockDim.x) sW[t] = W1[t];
    __syncthreads();
    int i = blockIdx.x * blockDim.x + threadIdx.x;
    if (i >= n) return;
    float xi[11];
#pragma unroll
    for (int k = 0; k < 11; k++) xi[k] = x[(size_t)i * 11 + k];
#pragma unroll
    for (int f = 0; f < 16; f++) {
        float acc = 0.0f;
#pragma unroll
        for (int k = 0; k < 11; k++) acc += xi[k] * sW[k * 16 + f];
        h1[(size_t)i * 16 + f] = acc;
    }
}

__global__ __launch_bounds__(256) void k_scatter16(const int* __restrict__ row,
                                                   const int* __restrict__ col,
                                                   const float* __restrict__ w,
                                                   const float* __restrict__ dinv,
                                                   const float* __restrict__ h1,
                                                   float* __restrict__ acc, int E) {
    int i = blockIdx.x * blockDim.x + threadIdx.x;
    if (i >= E) return;
    int r = row[i], c = col[i];
    float nw = dinv[r] * w[i] * dinv[c];
    const float4* hr = (const float4*)(h1 + (size_t)r * 16);
    float* o = acc + (size_t)c * 16;
#pragma unroll
    for (int q = 0; q < 4; q++) {
        float4 hv = hr[q];
        atomicAdd(o + q * 4 + 0, nw * hv.x);
        atomicAdd(o + q * 4 + 1, nw * hv.y);
        atomicAdd(o + q * 4 + 2, nw * hv.z);
        atomicAdd(o + q * 4 + 3, nw * hv.w);
    }
}

__global__ __launch_bounds__(256) void k_post1(const float* __restrict__ h1,
                                               const float* __restrict__ dinv,
                                               const float* __restrict__ b1,
                                               float* __restrict__ acc, int n) {
    int i = blockIdx.x * blockDim.x + threadIdx.x;
    if (i >= n) return;
    float dv = dinv[i];
    float cs = dv * dv;
#pragma unroll
    for (int f = 0; f < 16; f++) {
        float v = acc[(size_t)i * 16 + f] + cs * h1[(size_t)i * 16 + f] + b1[f];
        acc[(size_t)i * 16 + f] = v > 0.0f ? v : 0.0f;
    }
}

__global__ __launch_bounds__(256) void k_gemm2(const float* __restrict__ hrelu,
                                               const float* __restrict__ W2,
                                               float* __restrict__ h2, int n) {
    __shared__ float sW[32];
    for (int t = threadIdx.x; t < 32; t += blockDim.x) sW[t] = W2[t];
    __syncthreads();
    int i = blockIdx.x * blockDim.x + threadIdx.x;
    if (i >= n) return;
    float a0 = 0.0f, a1 = 0.0f;
#pragma unroll
    for (int f = 0; f < 16; f++) {
        float h = hrelu[(size_t)i * 16 + f];
        a0 += h * sW[f * 2 + 0];
        a1 += h * sW[f * 2 + 1];
    }
    h2[(size_t)i * 2 + 0] = a0;
    h2[(size_t)i * 2 + 1] = a1;
}

__global__ __launch_bounds__(256) void k_scatter2(const int* __restrict__ row,
                                                  const int* __restrict__ col,
                                                  const float* __restrict__ w,
                                                  const float* __restrict__ dinv,
                                                  const float* __restrict__ h2,
                                                  float* __restrict__ out, int E) {
    int i = blockIdx.x * blockDim.x + threadIdx.x;
    if (i >= E) return;
    int r = row[i], c = col[i];
    float nw = dinv[r] * w[i] * dinv[c];
    atomicAdd(&out[(size_t)c * 2 + 0], nw * h2[(size_t)r * 2 + 0]);
    atomicAdd(&out[(size_t)c * 2 + 1], nw * h2[(size_t)r * 2 + 1]);
}

__global__ __launch_bounds__(256) void k_final(const float* __restrict__ h2,
                                               const float* __restrict__ dinv,
                                               const float* __restrict__ b2,
                                               float* __restrict__ out, int n) {
    int i = blockIdx.x * blockDim.x + threadIdx.x;
    if (i >= n) return;
    float dv = dinv[i];
    float cs = dv * dv;
    float v0 = out[(size_t)i * 2 + 0] + cs * h2[(size_t)i * 2 + 0] + b2[0];
    float v1 = out[(size_t)i * 2 + 1] + cs * h2[(size_t)i * 2 + 1] + b2[1];
    float m = fmaxf(v0, v1);
    float lse = m + logf(expf(v0 - m) + expf(v1 - m));
    out[(size_t)i * 2 + 0] = v0 - lse;
    out[(size_t)i * 2 + 1] = v1 - lse;
}

// ---------------- launch ----------------

static inline size_t align64(size_t x) { return (x + 63) & ~(size_t)63; }

extern "C" void kernel_launch(void* const* d_in, const int* in_sizes, int n_in,
                              void* d_out, int out_size, void* d_ws, size_t ws_size,
                              hipStream_t stream) {
    const float* x  = (const float*)d_in[0];
    const int*   ei = (const int*)d_in[1];
    const float* ew = (const float*)d_in[2];
    const float* W1 = (const float*)d_in[3];
    const float* b1 = (const float*)d_in[4];
    const float* W2 = (const float*)d_in[5];
    const float* b2 = (const float*)d_in[6];

    const int n = in_sizes[0] / 11;
    const int E = in_sizes[2];
    const int* rowp = ei;       // sources
    const int* colp = ei + E;   // targets

    const int TB = 256;
    const int gN = (n + TB - 1) / TB;
    const int gE = (E + TB - 1) / TB;

    const int NB = (n + BKT - 1) / BKT;            // dst buckets
    const int CH = (E + NBLK - 1) / NBLK;          // edges per partition block

    float* outf = (float*)d_out;

    // config: SRCB=8 src windows (2MB xs working set per window)
    int SRCB = 8, SSH = 16;
    int use_csr = 1;
    size_t needed = 0;
    size_t o_hist, o_base, o_kb, o_dinv, o_xs, o_h2, o_run, o_edge, o_edge2;
    for (int attempt = 0; attempt < 3; attempt++) {
        int NKEY = NB * SRCB;
        size_t M = (size_t)NKEY * NBLK;
        o_hist = 0;
        o_base = align64(o_hist + M * 4);
        o_kb   = align64(o_base + M * 4);
        o_dinv = align64(o_kb + (size_t)NKEY * 4);
        o_xs   = align64(o_dinv + (size_t)n * 4);
        o_h2   = align64(o_xs + (size_t)n * 16 * 2);
        o_run  = align64(o_h2 + (size_t)n * 2 * 4);
        o_edge = align64(o_run + (use_csr ? ((size_t)(n + BKT + 1) * 4) : 0));
        o_edge2 = align64(o_edge + (size_t)E * 8);
        needed = use_csr ? align64(o_edge2 + (size_t)E * 8) : o_edge2;
        if (ws_size >= needed) break;
        if (attempt == 0) { use_csr = 0; }          // drop edge2+runstart
        else { SRCB = 1; SSH = 19; }                // plain bucket sort
    }

    if (ws_size >= needed && n <= (1 << 19) && NB <= NBMAX && NB * SRCB <= NKMAX) {
        char* base = (char*)d_ws;
        u32*   hist_g = (u32*)(base + o_hist);
        u32*   base_g = (u32*)(base + o_base);
        u32*   kb     = (u32*)(base + o_kb);
        float* dinv_g = (float*)(base + o_dinv);
        f16*   xs     = (f16*)(base + o_xs);
        float* h2s    = (float*)(base + o_h2);
        u32*   runst  = (u32*)(base + o_run);
        u64*   edge_g = (u64*)(base + o_edge);
        u64*   edge2_g = (u64*)(base + o_edge2);

        const int NKEY = NB * SRCB;
        const int KB = (NKEY + 255) / 256;

        k_count<<<NBLK, TB, 0, stream>>>(rowp, colp, hist_g, NKEY, SRCB, SSH, E, CH);
        k_colsum<<<KB, TB, 0, stream>>>(hist_g, kb, NKEY);
        k_scan_sums32<<<1, TB, 0, stream>>>(kb, NKEY);          // kb -> exclusive keybase
        k_basefill<<<KB, TB, 0, stream>>>(hist_g, kb, base_g, NKEY);
        k_scatter<<<NBLK, TB, 0, stream>>>(rowp, colp, ew, base_g, edge_g,
                                           NKEY, SRCB, SSH, E, CH);
        k_prep<<<NB, TB, 0, stream>>>(edge_g, kb, x, dinv_g, xs, SRCB, NB, n, E);
        if (use_csr) {
            k_pull16_csr<<<NB, 512, 0, stream>>>(edge_g, kb, edge2_g, runst, xs,
                                                 dinv_g, W1, b1, W2, h2s,
                                                 SRCB, NB, n, E);
            k_pull2_csr<<<gN, TB, 0, stream>>>(edge2_g, runst, h2s, dinv_g, b2,
                                               outf, n);
        } else {
            k_pull16_atomic<<<NB, 512, 0, stream>>>(edge_g, kb, xs, dinv_g,
                                                    W1, b1, W2, h2s, SRCB, NB, n, E);
            k_pull2_atomic<<<NB, 512, 0, stream>>>(edge_g, kb, h2s, dinv_g, b2,
                                                   outf, SRCB, NB, n, E);
        }
    } else {
        // fallback: atomic-scatter path (R1)
        float* ws   = (float*)d_ws;
        float* dinv = ws;
        float* h1   = ws + (size_t)n;
        float* acc1 = ws + (size_t)n * 17;

        k_init_deg<<<gN, TB, 0, stream>>>(dinv, n);
        k_deg_accum<<<gE, TB, 0, stream>>>(colp, ew, dinv, E);
        k_rsqrt<<<gN, TB, 0, stream>>>(dinv, n);

        k_gemm1_plain<<<gN, TB, 0, stream>>>(x, W1, h1, n);
        hipMemsetAsync(acc1, 0, (size_t)n * 16 * sizeof(float), stream);
        k_scatter16<<<gE, TB, 0, stream>>>(rowp, colp, ew, dinv, h1, acc1, E);
        k_post1<<<gN, TB, 0, stream>>>(h1, dinv, b1, acc1, n);

        float* h2 = h1;
        k_gemm2<<<gN, TB, 0, stream>>>(acc1, W2, h2, n);
        hipMemsetAsync(outf, 0, (size_t)n * 2 * sizeof(float), stream);
        k_scatter2<<<gE, TB, 0, stream>>>(rowp, colp, ew, dinv, h2, outf, E);
        k_final<<<gN, TB, 0, stream>>>(h2, dinv, b2, outf, n);
    }
}